// Round 1
// baseline (133.921 us; speedup 1.0000x reference)
//
#include <hip/hip_runtime.h>
#include <math.h>

// Problem constants
#define NB 2
#define HIMG 96
#define HO 65
#define NCROPS (NB*HO*HO)   // 8450

// pool1: [img][o1][o2][16ch][46][46]
#define P1_PLANE (46*46)          // 2116
#define P1_SIZE (8*16*P1_PLANE)   // 270848
// conv2: [img][o1][o2][32ch][44][44]
#define C2_PLANE (44*44)          // 1936
#define C2_SIZE (8*32*C2_PLANE)   // 495616
// pool2: [32 cls (img,o1,o2,p1,p2)][32ch][22][22]
#define P2_PLANE (22*22)          // 484
#define P2_SIZE (32*32*P2_PLANE)  // 495616
#define WT_SIZE (1152*128)        // 147456

// Fused conv1(5x5,1->16) + ReLU + 2x2 maxpool at parity (o1,o2).
__global__ void k_conv1pool(const float* __restrict__ x, const float* __restrict__ w1,
                            const float* __restrict__ b1, float* __restrict__ pool1) {
    int idx = blockIdx.x * 256 + threadIdx.x;     // < 270848
    int px = idx % 46;
    int t  = idx / 46;
    int py = t % 46;  t /= 46;
    int ch = t % 16;  t /= 16;                    // t = cls3 = (img*2+o1)*2+o2
    int o2 = t & 1, o1 = (t >> 1) & 1, img = t >> 2;
    const float* xim = x + img * (HIMG * HIMG);
    const float* wc  = w1 + ch * 25;
    float bias = b1[ch];
    float best = 0.f;   // relu'd values are >= 0
    #pragma unroll
    for (int dy = 0; dy < 2; ++dy) {
        int r = 2 * py + o1 + dy; if (r > 91) r = 91;
        #pragma unroll
        for (int dx = 0; dx < 2; ++dx) {
            int cc = 2 * px + o2 + dx; if (cc > 91) cc = 91;
            float s = bias;
            #pragma unroll
            for (int ky = 0; ky < 5; ++ky)
                #pragma unroll
                for (int kx = 0; kx < 5; ++kx)
                    s += xim[(r + ky) * 96 + cc + kx] * wc[ky * 5 + kx];
            best = fmaxf(best, s);
        }
    }
    pool1[idx] = best;
}

// conv2(3x3,16->32) + ReLU on each parity map.
__global__ void k_conv2(const float* __restrict__ pool1, const float* __restrict__ w2,
                        const float* __restrict__ b2, float* __restrict__ conv2) {
    int idx = blockIdx.x * 256 + threadIdx.x;     // < 495616
    int ox = idx % 44;
    int t  = idx / 44;
    int oy = t % 44;  t /= 44;
    int oc = t % 32;  t /= 32;                    // t = cls3
    const float* p1 = pool1 + t * 16 * P1_PLANE;
    float s = b2[oc];
    for (int ic = 0; ic < 16; ++ic) {
        const float* pp = p1 + ic * P1_PLANE;
        const float* ww = w2 + (oc * 16 + ic) * 9;
        #pragma unroll
        for (int ky = 0; ky < 3; ++ky)
            #pragma unroll
            for (int kx = 0; kx < 3; ++kx)
                s += pp[(oy + ky) * 46 + ox + kx] * ww[ky * 3 + kx];
    }
    conv2[idx] = fmaxf(s, 0.f);
}

// Second 2x2 maxpool at sub-parity (p1,p2) -> 32 classes.
__global__ void k_pool2(const float* __restrict__ conv2, float* __restrict__ pool2) {
    int idx = blockIdx.x * 256 + threadIdx.x;     // < 495616
    int ex = idx % 22;
    int t  = idx / 22;
    int ey = t % 22;  t /= 22;
    int ch = t % 32;  t /= 32;                    // t = cls5
    int p2 = t & 1, p1 = (t >> 1) & 1;
    int cls3 = t >> 2;
    const float* c2 = conv2 + (cls3 * 32 + ch) * C2_PLANE;
    int r0 = 2 * ey + p1, r1 = r0 + 1; if (r0 > 43) r0 = 43; if (r1 > 43) r1 = 43;
    int c0 = 2 * ex + p2, c1 = c0 + 1; if (c0 > 43) c0 = 43; if (c1 > 43) c1 = 43;
    float v = fmaxf(fmaxf(c2[r0 * 44 + c0], c2[r0 * 44 + c1]),
                    fmaxf(c2[r1 * 44 + c0], c2[r1 * 44 + c1]));
    pool2[idx] = v;
}

// wT[k][n] = fc1_w[n][k]
__global__ void k_transpose(const float* __restrict__ fc1_w, float* __restrict__ wT) {
    int idx = blockIdx.x * 256 + threadIdx.x;     // < 147456
    int n = idx & 127, k = idx >> 7;
    wT[idx] = fc1_w[n * 1152 + k];
}

__global__ void k_zero(float* __restrict__ out) {
    int i = blockIdx.x * 256 + threadIdx.x;
    if (i < NB * HIMG * HIMG) out[i] = 0.f;
}

// Fused: gather A-tile from pool2 classes -> LDS, GEMM (M=32 crops x N=128 x K=1152),
// FC1 bias+ReLU, FC2 + sigmoid, scatter to heatmap.
__global__ __launch_bounds__(256) void k_fc(const float* __restrict__ pool2,
                                            const float* __restrict__ wT,
                                            const float* __restrict__ fc1_b,
                                            const float* __restrict__ fc2_w,
                                            const float* __restrict__ fc2_b,
                                            float* __restrict__ out) {
    __shared__ float shA[64][32];
    __shared__ float shH[32][128];
    int tid = threadIdx.x;
    int m0  = blockIdx.x * 32;

    // --- staging mapping: thread owns crop (tid&31), k-group (tid>>5) ---
    int scrop = tid & 31;
    int kgrp  = tid >> 5;
    int crop_id = m0 + scrop;
    bool valid = crop_id < NCROPS;
    int cid = valid ? crop_id : 0;
    int img = cid / 4225;
    int rem = cid - img * 4225;
    int i = rem / 65;
    int j = rem - i * 65;
    int o1 = i & 1, p1 = (i >> 1) & 1, c = i >> 2;
    int o2 = j & 1, p2 = (j >> 1) & 1, d = j >> 2;
    int cls5 = (((img * 2 + o1) * 2 + o2) * 2 + p1) * 2 + p2;
    const float* pbase = pool2 + cls5 * 32 * P2_PLANE + c * 22 + d;

    // --- compute mapping: thread computes crops tm*4+{0..3} x outputs tn*4+{0..3} ---
    int tm = tid >> 5;   // 0..7
    int tn = tid & 31;   // 0..31
    float acc[4][4];
    #pragma unroll
    for (int r = 0; r < 4; ++r)
        #pragma unroll
        for (int s = 0; s < 4; ++s) acc[r][s] = 0.f;

    const float4* wp = (const float4*)wT;   // float4 index = k*32 + tn

    for (int ki = 0; ki < 18; ++ki) {
        __syncthreads();
        // stage 64 x 32 chunk of A (transposed: shA[k][crop])
        #pragma unroll
        for (int jj = 0; jj < 8; ++jj) {
            int kk = kgrp * 8 + jj;
            int k  = ki * 64 + kk;
            int ch = k / 36;
            int r2 = k - ch * 36;
            int mm = r2 / 6;
            int nn = r2 - mm * 6;
            float v = valid ? pbase[ch * P2_PLANE + mm * 22 + nn] : 0.f;
            shA[kk][scrop] = v;
        }
        __syncthreads();
        #pragma unroll 8
        for (int kk = 0; kk < 64; ++kk) {
            float4 a4 = *(const float4*)&shA[kk][tm * 4];
            float4 w4 = wp[(ki * 64 + kk) * 32 + tn];
            acc[0][0] += a4.x * w4.x; acc[0][1] += a4.x * w4.y;
            acc[0][2] += a4.x * w4.z; acc[0][3] += a4.x * w4.w;
            acc[1][0] += a4.y * w4.x; acc[1][1] += a4.y * w4.y;
            acc[1][2] += a4.y * w4.z; acc[1][3] += a4.y * w4.w;
            acc[2][0] += a4.z * w4.x; acc[2][1] += a4.z * w4.y;
            acc[2][2] += a4.z * w4.z; acc[2][3] += a4.z * w4.w;
            acc[3][0] += a4.w * w4.x; acc[3][1] += a4.w * w4.y;
            acc[3][2] += a4.w * w4.z; acc[3][3] += a4.w * w4.w;
        }
    }

    // FC1 bias + ReLU -> shH
    __syncthreads();
    float b0 = fc1_b[tn * 4 + 0], b1v = fc1_b[tn * 4 + 1];
    float b2v = fc1_b[tn * 4 + 2], b3 = fc1_b[tn * 4 + 3];
    #pragma unroll
    for (int r = 0; r < 4; ++r) {
        float4 h;
        h.x = fmaxf(acc[r][0] + b0, 0.f);
        h.y = fmaxf(acc[r][1] + b1v, 0.f);
        h.z = fmaxf(acc[r][2] + b2v, 0.f);
        h.w = fmaxf(acc[r][3] + b3, 0.f);
        *(float4*)&shH[tm * 4 + r][tn * 4] = h;
    }
    __syncthreads();

    // FC2: 8 threads per crop, each sums 16, shuffle-reduce.
    int crop_l = tid >> 3;
    int part   = tid & 7;
    const float* hh = shH[crop_l];
    float s = 0.f;
    #pragma unroll
    for (int u = 0; u < 16; ++u) s += hh[part * 16 + u] * fc2_w[part * 16 + u];
    s += __shfl_down(s, 4);
    s += __shfl_down(s, 2);
    s += __shfl_down(s, 1);
    if (part == 0) {
        int cid2 = m0 + crop_l;
        if (cid2 < NCROPS) {
            int img2 = cid2 / 4225;
            int rem2 = cid2 - img2 * 4225;
            int i2 = rem2 / 65;
            int j2 = rem2 - i2 * 65;
            float q = 1.f / (1.f + expf(-(s + fc2_b[0])));
            out[img2 * (HIMG * HIMG) + (16 + i2) * HIMG + (16 + j2)] = q;
        }
    }
}

extern "C" void kernel_launch(void* const* d_in, const int* in_sizes, int n_in,
                              void* d_out, int out_size, void* d_ws, size_t ws_size,
                              hipStream_t stream) {
    const float* x     = (const float*)d_in[0];
    const float* w1    = (const float*)d_in[1];
    const float* b1    = (const float*)d_in[2];
    const float* w2    = (const float*)d_in[3];
    const float* b2    = (const float*)d_in[4];
    const float* fc1_w = (const float*)d_in[5];
    const float* fc1_b = (const float*)d_in[6];
    const float* fc2_w = (const float*)d_in[7];
    const float* fc2_b = (const float*)d_in[8];
    float* out = (float*)d_out;

    float* ws    = (float*)d_ws;
    float* pool1 = ws;                       // 270848
    float* conv2 = pool1 + P1_SIZE;          // 495616
    float* pool2 = conv2 + C2_SIZE;          // 495616
    float* wT    = pool2 + P2_SIZE;          // 147456

    k_conv1pool<<<P1_SIZE / 256, 256, 0, stream>>>(x, w1, b1, pool1);
    k_transpose<<<WT_SIZE / 256, 256, 0, stream>>>(fc1_w, wT);
    k_conv2<<<C2_SIZE / 256, 256, 0, stream>>>(pool1, w2, b2, conv2);
    k_pool2<<<C2_SIZE / 256, 256, 0, stream>>>(conv2, pool2);
    k_zero<<<(NB * HIMG * HIMG + 255) / 256, 256, 0, stream>>>(out);
    k_fc<<<(NCROPS + 31) / 32, 256, 0, stream>>>(pool2, wT, fc1_b, fc2_w, fc2_b, out);
}

// Round 2
// 82.380 us; speedup vs baseline: 1.6256x; 1.6256x over previous
//
#include <hip/hip_runtime.h>
#include <math.h>

// Problem constants
#define NB 2
#define HIMG 96
#define HO 65
#define NCROPS (NB*HO*HO)   // 8450

// pool1: [img][o1][o2][16ch][46][46]
#define P1_PLANE (46*46)          // 2116
#define P1_SIZE (8*16*P1_PLANE)   // 270848
// conv2: [img][o1][o2][32ch][44][44]
#define C2_PLANE (44*44)          // 1936
#define C2_SIZE (8*32*C2_PLANE)   // 495616
// pool2: [32 cls (img,o1,o2,p1,p2)][32ch][22][22]
#define P2_PLANE (22*22)          // 484
#define P2_SIZE (32*32*P2_PLANE)  // 495616
#define WB_SIZE (128*1152)        // 147456 bf16

typedef __attribute__((ext_vector_type(8))) short bf16x8;
typedef __attribute__((ext_vector_type(4))) float f32x4;

__device__ __forceinline__ unsigned int f2bf(float x) {
    // RNE float->bf16 (finite values only)
    unsigned int u = __builtin_bit_cast(unsigned int, x);
    return (u + 0x7fffu + ((u >> 16) & 1u)) >> 16;
}

// Fused conv1(5x5,1->16) + ReLU + 2x2 maxpool at parity (o1,o2).
__global__ void k_conv1pool(const float* __restrict__ x, const float* __restrict__ w1,
                            const float* __restrict__ b1, float* __restrict__ pool1) {
    int idx = blockIdx.x * 256 + threadIdx.x;     // < 270848
    int px = idx % 46;
    int t  = idx / 46;
    int py = t % 46;  t /= 46;
    int ch = t % 16;  t /= 16;                    // t = cls3
    int o2 = t & 1, o1 = (t >> 1) & 1, img = t >> 2;
    const float* xim = x + img * (HIMG * HIMG);
    const float* wc  = w1 + ch * 25;
    float bias = b1[ch];
    float best = 0.f;
    #pragma unroll
    for (int dy = 0; dy < 2; ++dy) {
        int r = 2 * py + o1 + dy; if (r > 91) r = 91;
        #pragma unroll
        for (int dx = 0; dx < 2; ++dx) {
            int cc = 2 * px + o2 + dx; if (cc > 91) cc = 91;
            float s = bias;
            #pragma unroll
            for (int ky = 0; ky < 5; ++ky)
                #pragma unroll
                for (int kx = 0; kx < 5; ++kx)
                    s += xim[(r + ky) * 96 + cc + kx] * wc[ky * 5 + kx];
            best = fmaxf(best, s);
        }
    }
    pool1[idx] = best;
}

// conv2(3x3,16->32) + ReLU on each parity map.
__global__ void k_conv2(const float* __restrict__ pool1, const float* __restrict__ w2,
                        const float* __restrict__ b2, float* __restrict__ conv2) {
    int idx = blockIdx.x * 256 + threadIdx.x;     // < 495616
    int ox = idx % 44;
    int t  = idx / 44;
    int oy = t % 44;  t /= 44;
    int oc = t % 32;  t /= 32;                    // t = cls3
    const float* p1 = pool1 + t * 16 * P1_PLANE;
    float s = b2[oc];
    for (int ic = 0; ic < 16; ++ic) {
        const float* pp = p1 + ic * P1_PLANE;
        const float* ww = w2 + (oc * 16 + ic) * 9;
        #pragma unroll
        for (int ky = 0; ky < 3; ++ky)
            #pragma unroll
            for (int kx = 0; kx < 3; ++kx)
                s += pp[(oy + ky) * 46 + ox + kx] * ww[ky * 3 + kx];
    }
    conv2[idx] = fmaxf(s, 0.f);
}

// Second 2x2 maxpool at sub-parity (p1,p2) -> 32 classes.
__global__ void k_pool2(const float* __restrict__ conv2, float* __restrict__ pool2) {
    int idx = blockIdx.x * 256 + threadIdx.x;     // < 495616
    int ex = idx % 22;
    int t  = idx / 22;
    int ey = t % 22;  t /= 22;
    int ch = t % 32;  t /= 32;                    // t = cls5
    int p2 = t & 1, p1 = (t >> 1) & 1;
    int cls3 = t >> 2;
    const float* c2 = conv2 + (cls3 * 32 + ch) * C2_PLANE;
    int r0 = 2 * ey + p1, r1 = r0 + 1; if (r0 > 43) r0 = 43; if (r1 > 43) r1 = 43;
    int c0 = 2 * ex + p2, c1 = c0 + 1; if (c0 > 43) c0 = 43; if (c1 > 43) c1 = 43;
    float v = fmaxf(fmaxf(c2[r0 * 44 + c0], c2[r0 * 44 + c1]),
                    fmaxf(c2[r1 * 44 + c0], c2[r1 * 44 + c1]));
    pool2[idx] = v;
}

// wB[n][k] = bf16(fc1_w[n][k])  -- fc1_w is already [128][1152] row-major (B^T layout)
__global__ void k_castB(const float* __restrict__ fc1_w, unsigned short* __restrict__ wB) {
    int t = blockIdx.x * 256 + threadIdx.x;       // < 18432, handles 8 elements
    const float4* src = (const float4*)fc1_w + t * 2;
    float4 a = src[0], b = src[1];
    uint4 v;
    v.x = f2bf(a.x) | (f2bf(a.y) << 16);
    v.y = f2bf(a.z) | (f2bf(a.w) << 16);
    v.z = f2bf(b.x) | (f2bf(b.y) << 16);
    v.w = f2bf(b.z) | (f2bf(b.w) << 16);
    ((uint4*)wB)[t] = v;
}

__global__ void k_zero(float* __restrict__ out) {
    int i = blockIdx.x * 256 + threadIdx.x;
    if (i < NB * HIMG * HIMG) out[i] = 0.f;
}

// Fused MFMA GEMM: gather A (32 crops x 1152) from pool2, B = wB (128 x 1152 bf16),
// C = A*B^T (fp32 acc), then bias+ReLU -> FC2 -> sigmoid -> scatter.
// Block: 256 thr = 4 waves (2x2), wave tile 16(M) x 64(N), K-step 32, double-buffered LDS.
__global__ __launch_bounds__(256) void k_fc(const float* __restrict__ pool2,
                                            const unsigned short* __restrict__ wB,
                                            const float* __restrict__ fc1_b,
                                            const float* __restrict__ fc2_w,
                                            const float* __restrict__ fc2_b,
                                            float* __restrict__ out) {
    __shared__ __align__(16) unsigned short shA[2][32][40];   // pad 40: <=2-way bank conflict
    __shared__ __align__(16) unsigned short shB[2][128][40];
    __shared__ __align__(16) float shH[32][132];
    __shared__ __align__(16) unsigned int shOff[1152];        // k -> pool2 window offset

    int tid = threadIdx.x;
    int m0  = blockIdx.x * 32;

    // Build gather-offset table: k = ch*36 + mm*6 + nn -> ch*484 + mm*22 + nn
    for (int k = tid; k < 1152; k += 256) {
        int ch = k / 36, rr = k - ch * 36, mm = rr / 6, nn = rr - mm * 6;
        shOff[k] = ch * P2_PLANE + mm * 22 + nn;
    }

    // A-gather setup (threads 0..127: row = tid>>2 in [0,32), k-quarter = tid&3)
    int arow = tid >> 2, akq = tid & 3;
    int cid = m0 + arow;
    bool avalid = (tid < 128) && (cid < NCROPS);
    int cidc = cid < NCROPS ? cid : NCROPS - 1;
    int img = cidc / 4225;
    int rem = cidc - img * 4225;
    int i = rem / 65, j = rem - i * 65;
    int o1 = i & 1, p1 = (i >> 1) & 1, c = i >> 2;
    int o2 = j & 1, p2 = (j >> 1) & 1, d = j >> 2;
    int cls5 = (((img * 2 + o1) * 2 + o2) * 2 + p1) * 2 + p2;
    const float* pbase = pool2 + cls5 * 32 * P2_PLANE + c * 22 + d;

    // B staging setup (all threads: row = tid>>1 in [0,128), half = tid&1)
    int brow = tid >> 1, bh = tid & 1;
    const unsigned short* bg = wB + brow * 1152 + bh * 16;

    __syncthreads();   // shOff ready

    float aval[8];
    uint4 bv0, bv1;

    auto LOADS = [&](int ki) {
        if (tid < 128) {
            const uint4* qp = (const uint4*)&shOff[ki * 32 + akq * 8];
            uint4 q0 = qp[0], q1 = qp[1];
            unsigned idx0 = q0.x, idx1 = q0.y, idx2 = q0.z, idx3 = q0.w;
            unsigned idx4 = q1.x, idx5 = q1.y, idx6 = q1.z, idx7 = q1.w;
            aval[0] = avalid ? pbase[idx0] : 0.f;
            aval[1] = avalid ? pbase[idx1] : 0.f;
            aval[2] = avalid ? pbase[idx2] : 0.f;
            aval[3] = avalid ? pbase[idx3] : 0.f;
            aval[4] = avalid ? pbase[idx4] : 0.f;
            aval[5] = avalid ? pbase[idx5] : 0.f;
            aval[6] = avalid ? pbase[idx6] : 0.f;
            aval[7] = avalid ? pbase[idx7] : 0.f;
        }
        const uint4* bp = (const uint4*)(bg + ki * 32);
        bv0 = bp[0]; bv1 = bp[1];
    };
    auto WRITE = [&](int buf) {
        if (tid < 128) {
            uint4 av;
            av.x = f2bf(aval[0]) | (f2bf(aval[1]) << 16);
            av.y = f2bf(aval[2]) | (f2bf(aval[3]) << 16);
            av.z = f2bf(aval[4]) | (f2bf(aval[5]) << 16);
            av.w = f2bf(aval[6]) | (f2bf(aval[7]) << 16);
            *(uint4*)&shA[buf][arow][akq * 8] = av;
        }
        *(uint4*)&shB[buf][brow][bh * 16]     = bv0;
        *(uint4*)&shB[buf][brow][bh * 16 + 8] = bv1;
    };

    // Compute mapping: 4 waves in 2x2; wave tile 16(M) x 64(N)
    int lane = tid & 63, wid = tid >> 6;
    int wr = wid >> 1, wc = wid & 1;
    int lm = lane & 15, lg = lane >> 4;

    f32x4 acc[4];
    #pragma unroll
    for (int ni = 0; ni < 4; ++ni) acc[ni] = (f32x4){0.f, 0.f, 0.f, 0.f};

    LOADS(0);
    WRITE(0);
    __syncthreads();

    for (int ki = 0; ki < 36; ++ki) {
        int cur = ki & 1;
        if (ki < 35) LOADS(ki + 1);   // prefetch next K-step into regs (overlaps MFMA)
        bf16x8 a = *(const bf16x8*)&shA[cur][wr * 16 + lm][lg * 8];
        #pragma unroll
        for (int ni = 0; ni < 4; ++ni) {
            bf16x8 b = *(const bf16x8*)&shB[cur][wc * 64 + ni * 16 + lm][lg * 8];
            acc[ni] = __builtin_amdgcn_mfma_f32_16x16x32_bf16(a, b, acc[ni], 0, 0, 0);
        }
        if (ki < 35) WRITE(cur ^ 1);
        __syncthreads();
    }

    // FC1 bias + ReLU -> shH.  C/D layout: col = lane&15, row = (lane>>4)*4 + r
    float bias[4];
    #pragma unroll
    for (int ni = 0; ni < 4; ++ni) bias[ni] = fc1_b[wc * 64 + ni * 16 + lm];
    #pragma unroll
    for (int ni = 0; ni < 4; ++ni)
        #pragma unroll
        for (int r = 0; r < 4; ++r)
            shH[wr * 16 + lg * 4 + r][wc * 64 + ni * 16 + lm] =
                fmaxf(acc[ni][r] + bias[ni], 0.f);
    __syncthreads();

    // FC2: 8 threads per crop, each sums 16, shuffle-reduce, sigmoid, scatter.
    int crop_l = tid >> 3, part = tid & 7;
    const float* hh = shH[crop_l];
    float s = 0.f;
    #pragma unroll
    for (int u = 0; u < 16; ++u) s += hh[part * 16 + u] * fc2_w[part * 16 + u];
    s += __shfl_down(s, 4);
    s += __shfl_down(s, 2);
    s += __shfl_down(s, 1);
    if (part == 0) {
        int cid2 = m0 + crop_l;
        if (cid2 < NCROPS) {
            int img2 = cid2 / 4225;
            int rem2 = cid2 - img2 * 4225;
            int i2 = rem2 / 65, j2 = rem2 - i2 * 65;
            float q = 1.f / (1.f + expf(-(s + fc2_b[0])));
            out[img2 * (HIMG * HIMG) + (16 + i2) * HIMG + (16 + j2)] = q;
        }
    }
}

extern "C" void kernel_launch(void* const* d_in, const int* in_sizes, int n_in,
                              void* d_out, int out_size, void* d_ws, size_t ws_size,
                              hipStream_t stream) {
    const float* x     = (const float*)d_in[0];
    const float* w1    = (const float*)d_in[1];
    const float* b1    = (const float*)d_in[2];
    const float* w2    = (const float*)d_in[3];
    const float* b2    = (const float*)d_in[4];
    const float* fc1_w = (const float*)d_in[5];
    const float* fc1_b = (const float*)d_in[6];
    const float* fc2_w = (const float*)d_in[7];
    const float* fc2_b = (const float*)d_in[8];
    float* out = (float*)d_out;

    float* ws    = (float*)d_ws;
    float* pool1 = ws;                         // 270848 f32
    float* conv2 = pool1 + P1_SIZE;            // 495616 f32
    float* pool2 = conv2 + C2_SIZE;            // 495616 f32
    unsigned short* wB = (unsigned short*)(pool2 + P2_SIZE);  // 147456 bf16

    k_conv1pool<<<P1_SIZE / 256, 256, 0, stream>>>(x, w1, b1, pool1);
    k_castB<<<WB_SIZE / 8 / 256, 256, 0, stream>>>(fc1_w, wB);
    k_conv2<<<C2_SIZE / 256, 256, 0, stream>>>(pool1, w2, b2, conv2);
    k_pool2<<<C2_SIZE / 256, 256, 0, stream>>>(conv2, pool2);
    k_zero<<<(NB * HIMG * HIMG + 255) / 256, 256, 0, stream>>>(out);
    k_fc<<<(NCROPS + 31) / 32, 256, 0, stream>>>(pool2, wB, fc1_b, fc2_w, fc2_b, out);
}

// Round 3
// 61.730 us; speedup vs baseline: 2.1695x; 1.3345x over previous
//
#include <hip/hip_runtime.h>
#include <math.h>

// Problem constants
#define NB 2
#define HIMG 96
#define HO 65
#define NCROPS (NB*HO*HO)   // 8450

// pool1: [cls3=(img,o1,o2)][16ch][46][46]
#define P1_PLANE (46*46)          // 2116
#define P1_SIZE (8*16*P1_PLANE)   // 270848
// conv2: [cls3][32ch][44][44]
#define C2_PLANE (44*44)          // 1936
#define C2_SIZE (8*32*C2_PLANE)   // 495616
// pool2: [cls5=(img,o1,o2,p1,p2)][32ch][22][22]
#define P2_PLANE (22*22)          // 484
#define P2_SIZE (32*32*P2_PLANE)  // 495616
#define WB_SIZE (128*1152)        // bf16 elements

typedef __attribute__((ext_vector_type(8))) short bf16x8;
typedef __attribute__((ext_vector_type(4))) float f32x4;

__device__ __forceinline__ unsigned int f2bf(float x) {
    unsigned int u = __builtin_bit_cast(unsigned int, x);
    return (u + 0x7fffu + ((u >> 16) & 1u)) >> 16;
}

// Fused conv1(5x5,1->16)+ReLU+2x2 maxpool at parity (o1,o2); 2 outputs/thread.
// Edge cells whose windows would run past row/col 95 are garbage-but-unused
// (only crops i,j<=64 consume the maps; clamp keeps loads in-bounds).
__global__ void k_conv1pool(const float* __restrict__ x, const float* __restrict__ w1,
                            const float* __restrict__ b1, float* __restrict__ pool1) {
    int idx = blockIdx.x * 256 + threadIdx.x;     // < 135424
    int pg = idx % 23;
    int t  = idx / 23;
    int py = t % 46;  t /= 46;
    int ch = t % 16;  t /= 16;                    // t = cls3
    int o2 = t & 1, o1 = (t >> 1) & 1, img = t >> 2;
    const float* xim = x + img * (HIMG * HIMG);

    int rbase = 2 * py + o1;
    int cbase = 4 * pg + o2;
    float a[6][8];
    #pragma unroll
    for (int i = 0; i < 6; ++i) {
        int r = rbase + i; if (r > 95) r = 95;
        const float* rp = xim + r * 96;
        #pragma unroll
        for (int j = 0; j < 8; ++j) {
            int c = cbase + j; if (c > 95) c = 95;
            a[i][j] = rp[c];
        }
    }
    const float* wc = w1 + ch * 25;
    float w[25];
    #pragma unroll
    for (int u = 0; u < 25; ++u) w[u] = wc[u];
    float bias = b1[ch];

    float out0 = 0.f, out1 = 0.f;   // relu'd values >= 0
    #pragma unroll
    for (int dy = 0; dy < 2; ++dy)
        #pragma unroll
        for (int dx = 0; dx < 2; ++dx) {
            float s0 = bias, s1 = bias;
            #pragma unroll
            for (int ky = 0; ky < 5; ++ky)
                #pragma unroll
                for (int kx = 0; kx < 5; ++kx) {
                    float wv = w[ky * 5 + kx];
                    s0 += a[dy + ky][dx + kx] * wv;
                    s1 += a[dy + ky][2 + dx + kx] * wv;
                }
            out0 = fmaxf(out0, s0);
            out1 = fmaxf(out1, s1);
        }
    int base = ((t * 16 + ch) * 46 + py) * 46 + 2 * pg;
    float2 v; v.x = out0; v.y = out1;
    *(float2*)&pool1[base] = v;
}

// conv2(3x3,16->32)+ReLU; 4 outputs along x per thread, float4 store.
__global__ void k_conv2(const float* __restrict__ pool1, const float* __restrict__ w2,
                        const float* __restrict__ b2, float* __restrict__ conv2) {
    int idx = blockIdx.x * 256 + threadIdx.x;     // < 123904
    int og = idx % 11;
    int t  = idx / 11;
    int oy = t % 44;  t /= 44;
    int oc = t % 32;  t /= 32;                    // t = cls3
    int ox0 = og * 4;
    const float* p1 = pool1 + t * 16 * P1_PLANE + oy * 46 + ox0;
    const float* ww = w2 + oc * 144;
    float b = b2[oc];
    float s0 = b, s1 = b, s2 = b, s3 = b;
    for (int ic = 0; ic < 16; ++ic) {
        const float* pp = p1 + ic * P1_PLANE;
        const float* wk = ww + ic * 9;
        #pragma unroll
        for (int ky = 0; ky < 3; ++ky) {
            const float* r = pp + ky * 46;
            float w0 = wk[ky * 3], w1v = wk[ky * 3 + 1], w2v = wk[ky * 3 + 2];
            float a0 = r[0], a1 = r[1], a2 = r[2], a3 = r[3], a4 = r[4], a5 = r[5];
            s0 += a0 * w0 + a1 * w1v + a2 * w2v;
            s1 += a1 * w0 + a2 * w1v + a3 * w2v;
            s2 += a2 * w0 + a3 * w1v + a4 * w2v;
            s3 += a3 * w0 + a4 * w1v + a5 * w2v;
        }
    }
    float4 v;
    v.x = fmaxf(s0, 0.f); v.y = fmaxf(s1, 0.f);
    v.z = fmaxf(s2, 0.f); v.w = fmaxf(s3, 0.f);
    *(float4*)&conv2[(t * 32 + oc) * C2_PLANE + oy * 44 + ox0] = v;
}

// Second 2x2 maxpool at sub-parity (p1,p2) -> 32 classes.
__global__ void k_pool2(const float* __restrict__ conv2, float* __restrict__ pool2) {
    int idx = blockIdx.x * 256 + threadIdx.x;     // < 495616
    int ex = idx % 22;
    int t  = idx / 22;
    int ey = t % 22;  t /= 22;
    int ch = t % 32;  t /= 32;                    // t = cls5
    int p2 = t & 1, p1 = (t >> 1) & 1;
    int cls3 = t >> 2;
    const float* c2 = conv2 + (cls3 * 32 + ch) * C2_PLANE;
    int r0 = 2 * ey + p1, r1 = r0 + 1; if (r0 > 43) r0 = 43; if (r1 > 43) r1 = 43;
    int c0 = 2 * ex + p2, c1 = c0 + 1; if (c0 > 43) c0 = 43; if (c1 > 43) c1 = 43;
    float v = fmaxf(fmaxf(c2[r0 * 44 + c0], c2[r0 * 44 + c1]),
                    fmaxf(c2[r1 * 44 + c0], c2[r1 * 44 + c1]));
    pool2[idx] = v;
}

// Merged: cast fc1_w -> bf16 wB (blocks 0..71), zero heatmap (blocks 72..143).
__global__ void k_misc(const float* __restrict__ fc1_w, unsigned short* __restrict__ wB,
                       float* __restrict__ out) {
    int b = blockIdx.x, tid = threadIdx.x;
    if (b < 72) {
        int t = b * 256 + tid;                    // < 18432, 8 elements each
        const float4* src = (const float4*)fc1_w + t * 2;
        float4 a = src[0], c = src[1];
        uint4 v;
        v.x = f2bf(a.x) | (f2bf(a.y) << 16);
        v.y = f2bf(a.z) | (f2bf(a.w) << 16);
        v.z = f2bf(c.x) | (f2bf(c.y) << 16);
        v.w = f2bf(c.z) | (f2bf(c.w) << 16);
        ((uint4*)wB)[t] = v;
    } else {
        out[(b - 72) * 256 + tid] = 0.f;
    }
}

// Fused MFMA GEMM, barrier-free main loop.
// Block: 512 thr (8 waves). A-panel (32 crops x 1152) gathered once into LDS.
// Each wave owns a 16-wide N-slice; B fragments straight from L2-hot wB
// (each B byte read exactly once per block). 36 K-steps, no syncthreads inside.
__global__ __launch_bounds__(512) void k_fc(const float* __restrict__ pool2,
                                            const unsigned short* __restrict__ wB,
                                            const float* __restrict__ fc1_b,
                                            const float* __restrict__ fc2_w,
                                            const float* __restrict__ fc2_b,
                                            float* __restrict__ out) {
    __shared__ __align__(16) union ShMem {
        unsigned short a[32][1160];   // pad 8 shorts: frag reads are 2-way conflict (free)
        float h[32][132];             // epilogue overlay
    } sh;

    int tid = threadIdx.x;
    int m0  = blockIdx.x * 32;

    // ---- Stage A: thread = (arow = tid>>4, kseg = tid&15); 72 k's = channels 2k..2k+1
    int arow = tid >> 4, kseg = tid & 15;
    int cid = m0 + arow;
    bool avalid = cid < NCROPS;
    int cidc = avalid ? cid : NCROPS - 1;
    int img = cidc / 4225;
    int rem = cidc - img * 4225;
    int i = rem / 65, j = rem - i * 65;
    int o1 = i & 1, p1 = (i >> 1) & 1, c = i >> 2;
    int o2 = j & 1, p2 = (j >> 1) & 1, d = j >> 2;
    int cls5 = (((img * 2 + o1) * 2 + o2) * 2 + p1) * 2 + p2;
    const float* pbase = pool2 + cls5 * 32 * P2_PLANE + c * 22 + d;

    {
        unsigned int v[36];
        #pragma unroll
        for (int cc = 0; cc < 2; ++cc) {
            const float* p = pbase + (2 * kseg + cc) * P2_PLANE;
            #pragma unroll
            for (int mm = 0; mm < 6; ++mm)
                #pragma unroll
                for (int e = 0; e < 3; ++e) {
                    float x0 = p[mm * 22 + 2 * e];
                    float x1 = p[mm * 22 + 2 * e + 1];
                    v[cc * 18 + mm * 3 + e] = f2bf(x0) | (f2bf(x1) << 16);
                }
        }
        uint4* dst = (uint4*)&sh.a[arow][kseg * 72];
        #pragma unroll
        for (int q = 0; q < 9; ++q) {
            uint4 w; w.x = v[q*4]; w.y = v[q*4+1]; w.z = v[q*4+2]; w.w = v[q*4+3];
            dst[q] = w;
        }
    }

    // ---- Main loop: wave wid covers N-cols [wid*16, wid*16+16)
    int lane = tid & 63, wid = tid >> 6;
    int lm = lane & 15, lg = lane >> 4;

    const unsigned short* bp  = wB + (wid * 16 + lm) * 1152 + lg * 8;
    const unsigned short* a0p = &sh.a[lm][lg * 8];
    const unsigned short* a1p = &sh.a[16 + lm][lg * 8];

    f32x4 acc0 = {0.f, 0.f, 0.f, 0.f};
    f32x4 acc1 = {0.f, 0.f, 0.f, 0.f};

    __syncthreads();

    #pragma unroll 4
    for (int ki = 0; ki < 36; ++ki) {
        bf16x8 av0 = *(const bf16x8*)(a0p + ki * 32);
        bf16x8 av1 = *(const bf16x8*)(a1p + ki * 32);
        bf16x8 bv  = *(const bf16x8*)(bp + ki * 32);
        acc0 = __builtin_amdgcn_mfma_f32_16x16x32_bf16(av0, bv, acc0, 0, 0, 0);
        acc1 = __builtin_amdgcn_mfma_f32_16x16x32_bf16(av1, bv, acc1, 0, 0, 0);
    }

    // ---- Epilogue: bias+ReLU into H overlay (C/D: col=lm, row=lg*4+r)
    __syncthreads();   // all A reads done before overlay write
    float bias = fc1_b[wid * 16 + lm];
    #pragma unroll
    for (int r = 0; r < 4; ++r) {
        sh.h[lg * 4 + r][wid * 16 + lm]      = fmaxf(acc0[r] + bias, 0.f);
        sh.h[16 + lg * 4 + r][wid * 16 + lm] = fmaxf(acc1[r] + bias, 0.f);
    }
    __syncthreads();

    // ---- FC2: 16 threads per crop (crop_l == arow), 8 elems each, shuffle-reduce
    int part = tid & 15;
    const float* hh = sh.h[arow];
    float s = 0.f;
    #pragma unroll
    for (int u = 0; u < 8; ++u) s += hh[part * 8 + u] * fc2_w[part * 8 + u];
    s += __shfl_down(s, 8);
    s += __shfl_down(s, 4);
    s += __shfl_down(s, 2);
    s += __shfl_down(s, 1);
    if (part == 0 && avalid) {
        float q = 1.f / (1.f + expf(-(s + fc2_b[0])));
        out[img * (HIMG * HIMG) + (16 + i) * HIMG + (16 + j)] = q;
    }
}

extern "C" void kernel_launch(void* const* d_in, const int* in_sizes, int n_in,
                              void* d_out, int out_size, void* d_ws, size_t ws_size,
                              hipStream_t stream) {
    const float* x     = (const float*)d_in[0];
    const float* w1    = (const float*)d_in[1];
    const float* b1    = (const float*)d_in[2];
    const float* w2    = (const float*)d_in[3];
    const float* b2    = (const float*)d_in[4];
    const float* fc1_w = (const float*)d_in[5];
    const float* fc1_b = (const float*)d_in[6];
    const float* fc2_w = (const float*)d_in[7];
    const float* fc2_b = (const float*)d_in[8];
    float* out = (float*)d_out;

    float* ws    = (float*)d_ws;
    float* pool1 = ws;                         // 270848 f32
    float* conv2 = pool1 + P1_SIZE;            // 495616 f32
    float* pool2 = conv2 + C2_SIZE;            // 495616 f32
    unsigned short* wB = (unsigned short*)(pool2 + P2_SIZE);  // 147456 bf16

    k_conv1pool<<<529, 256, 0, stream>>>(x, w1, b1, pool1);
    k_misc<<<144, 256, 0, stream>>>(fc1_w, wB, out);
    k_conv2<<<484, 256, 0, stream>>>(pool1, w2, b2, conv2);
    k_pool2<<<C2_SIZE / 256, 256, 0, stream>>>(conv2, pool2);
    k_fc<<<(NCROPS + 31) / 32, 512, 0, stream>>>(pool2, wB, fc1_b, fc2_w, fc2_b, out);
}